// Round 3
// baseline (2178.521 us; speedup 1.0000x reference)
//
#include <hip/hip_runtime.h>
#include <cstdint>
#include <math.h>

// Problem constants (fixed by reference setup_inputs)
#define B_IMG   8
#define N_PROP  16384
#define NCAND   16384        // per-(image,label) candidate array stride
#define NMS_MAX 640
#define DETS    320
#define SCORE_TH 0.3f
#define MIN_SZ   0.01f
#define BBOX_CLIP_F 4.135166556742356f   // log(1000/16), same f32 as reference

// Exact threshold for "RN_f32(inter/denom) > 0.3f" without dividing:
// 0.3f = 0x3E99999A (even mantissa), succ = 0x3E99999B.
// q > 0.3f  <=>  inter/denom (real) > midpoint(0.3f, succ)  (tie->even rounds DOWN to 0.3f)
// midpoint is exact in f64; (25-bit m) * (24-bit denom) product is exact in f64.
#define M_TH 0.30000002682209014892578125

#define NMS_THREADS 512
#define NW          (NMS_THREADS/64)     // 8 waves
#define RSLOTS      18                   // register slots/thread -> 9216 capacity (V ~ 7700 +- 64)
#define REGCAP      (NMS_THREADS*RSLOTS)

// -------- Phase A: decode + softmax + validity -> compacted per-(b,label) lists --------
__global__ __launch_bounds__(256) void decode_compact(
    const float* __restrict__ logits, const float* __restrict__ rel,
    const float* __restrict__ props, const int* __restrict__ img_size,
    int* __restrict__ cnt, float* __restrict__ sc_ws, int* __restrict__ n_ws,
    float4* __restrict__ ob_ws, float4* __restrict__ rb_ws)
{
    int t = blockIdx.x * 256 + threadIdx.x;     // t in [0, B*N)
    int b = t >> 14;
    int n = t & (N_PROP - 1);
    float fs = (float)img_size[0];

    float l0 = logits[3*t+0], l1 = logits[3*t+1], l2 = logits[3*t+2];
    float m  = fmaxf(l0, fmaxf(l1, l2));
    float e0 = expf(l0 - m), e1 = expf(l1 - m), e2 = expf(l2 - m);
    float sum = e0 + e1 + e2;
    float p[2] = { e1 / sum, e2 / sum };

    float4 pr = reinterpret_cast<const float4*>(props)[t];
    float w  = pr.z - pr.x, h  = pr.w - pr.y;
    float cx = pr.x + 0.5f*w, cy = pr.y + 0.5f*h;

    const float4* relv = reinterpret_cast<const float4*>(rel) + 3*t;
    int lane = threadIdx.x & 63;
    unsigned long long lanemask = (1ull << lane) - 1ull;

    #pragma unroll
    for (int c = 1; c <= 2; ++c) {
        float4 r = relv[c];
        float dx = r.x / 10.0f, dy = r.y / 10.0f;
        float dw = fminf(r.z / 5.0f, BBOX_CLIP_F);
        float dh = fminf(r.w / 5.0f, BBOX_CLIP_F);
        float pcx = dx * w + cx, pcy = dy * h + cy;
        float pw  = expf(dw) * w, ph  = expf(dh) * h;
        float x1 = pcx - 0.5f*pw, y1 = pcy - 0.5f*ph;
        float x2 = pcx + 0.5f*pw, y2 = pcy + 0.5f*ph;
        x1 = fminf(fmaxf(x1, 0.f), fs); y1 = fminf(fmaxf(y1, 0.f), fs);
        x2 = fminf(fmaxf(x2, 0.f), fs); y2 = fminf(fmaxf(y2, 0.f), fs);
        float sc = p[c-1];
        bool valid = (sc > SCORE_TH) && (x2 - x1 >= MIN_SZ) && (y2 - y1 >= MIN_SZ);

        unsigned long long mball = __ballot(valid);
        int g   = b*2 + (c-1);
        int tot = __popcll(mball);
        int base = 0;
        if (lane == 0 && tot > 0) base = atomicAdd(&cnt[g], tot);
        base = __shfl(base, 0);
        if (valid) {
            int slot = g*NCAND + base + __popcll(mball & lanemask);
            sc_ws[slot] = sc;
            n_ws[slot]  = n;                     // original proposal index (flat idx j = 2n+c-1)
            float off = (float)c * (fs + 1.0f);  // matches reference nboxes bit-for-bit
            ob_ws[slot] = make_float4(x1+off, y1+off, x2+off, y2+off);
            rb_ws[slot] = make_float4(x1, y1, x2, y2);
        }
    }
}

// -------- Phase B: per-(image,label) greedy NMS, register-resident, no spill --------
__global__ __launch_bounds__(NMS_THREADS, 1) void nms_greedy(
    float* __restrict__ sc_ws, const int* __restrict__ n_ws,
    const float4* __restrict__ ob_ws, const float4* __restrict__ rb_ws,
    const int* __restrict__ cnt, int* __restrict__ Kout,
    float* __restrict__ survS, int* __restrict__ survN, float4* __restrict__ survB)
{
    __shared__ unsigned long long warpKey[2][NW];   // parity double-buffer: 1 barrier/iter
    __shared__ int                warpSlot[2][NW];
    __shared__ float4             warpBox[2][NW];
    __shared__ float sS[NMS_MAX];                   // survivors staged in LDS, flushed after loop
    __shared__ int   sN[NMS_MAX];
    __shared__ int   sSlot[NMS_MAX];

    int g   = blockIdx.x;            // g = b*2 + (label-1)
    int tid = threadIdx.x;
    int V   = cnt[g];
    float*        gsc  = sc_ws + g*NCAND;
    const float4* obox = ob_ws + g*NCAND;
    const int*    nn   = n_ws  + g*NCAND;

    // load candidates into registers (coalesced: slot i = k*512 + tid)
    unsigned long long key_r[RSLOTS];
    float4 bx_r[RSLOTS];
    float  a2_r[RSLOTS];
    #pragma unroll
    for (int k = 0; k < RSLOTS; ++k) {
        int i = k*NMS_THREADS + tid;
        if (i < V) {
            float s = gsc[i];
            key_r[k] = ((unsigned long long)__float_as_uint(s) << 32) | (unsigned)(~nn[i]);
            float4 bx = obox[i];
            bx_r[k] = bx;
            a2_r[k] = (bx.z - bx.x) * (bx.w - bx.y);
        } else {
            key_r[k] = 0ull;
            bx_r[k] = make_float4(0.f, 0.f, 0.f, 0.f);
            a2_r[k] = 0.f;
        }
    }

    float4 prev = make_float4(-2.f, -2.f, -1.f, -1.f);   // dummy: IoU vs anything = 0
    int wid = tid >> 6, lane = tid & 63;
    int K = 0;

    for (int it = 0; it < NMS_MAX; ++it) {
        int p = it & 1;
        float a1 = (prev.z - prev.x) * (prev.w - prev.y);
        unsigned long long best = 0ull;
        int bslot = 0;
        float4 bestBox = make_float4(0.f, 0.f, 0.f, 0.f);

        #pragma unroll
        for (int k = 0; k < RSLOTS; ++k) {
            if (k*NMS_THREADS < V) {             // uniform branch: skip fully-empty tail
                unsigned long long key = key_r[k];
                if (key) {
                    float4 bx = bx_r[k];
                    float ltx = fmaxf(prev.x, bx.x), lty = fmaxf(prev.y, bx.y);
                    float rbx = fminf(prev.z, bx.z), rby = fminf(prev.w, bx.w);
                    float ww = fmaxf(rbx - ltx, 0.f), hh = fmaxf(rby - lty, 0.f);
                    float inter = ww * hh;
                    float denom = (a1 + a2_r[k]) - inter;
                    if ((double)inter > M_TH * (double)denom) {   // exact: iou > 0.3f
                        key_r[k] = 0ull;                           // suppressed (incl. self)
                    } else if (key > best) {
                        best = key; bslot = k*NMS_THREADS + tid; bestBox = bx;
                    }
                }
            }
        }
        // global tail for V > REGCAP (normally never taken)
        for (int i = REGCAP + tid; i < V; i += NMS_THREADS) {
            float s = gsc[i];
            if (s > 0.f) {
                float4 bx = obox[i];
                float ltx = fmaxf(prev.x, bx.x), lty = fmaxf(prev.y, bx.y);
                float rbx = fminf(prev.z, bx.z), rby = fminf(prev.w, bx.w);
                float ww = fmaxf(rbx - ltx, 0.f), hh = fmaxf(rby - lty, 0.f);
                float inter = ww * hh;
                float a2 = (bx.z - bx.x) * (bx.w - bx.y);
                float denom = (a1 + a2) - inter;
                if ((double)inter > M_TH * (double)denom) {
                    gsc[i] = 0.f;
                } else {
                    unsigned long long key =
                        ((unsigned long long)__float_as_uint(s) << 32) | (unsigned)(~nn[i]);
                    if (key > best) { best = key; bslot = i; bestBox = bx; }
                }
            }
        }

        // warp-level max key; winner located by ballot (keys are unique: ~n embedded)
        unsigned long long wmax = best;
        #pragma unroll
        for (int off = 32; off > 0; off >>= 1) {
            unsigned long long o = __shfl_down(wmax, off);
            if (o > wmax) wmax = o;
        }
        wmax = __shfl(wmax, 0);
        unsigned long long wb = __ballot(best == wmax && wmax != 0ull);
        int wl = __ffsll((long long)wb) - 1;       // -1 if warp fully dead
        int srcl = (wl < 0) ? 0 : wl;
        int    wslot = __shfl(bslot, srcl);
        float4 wbox;
        wbox.x = __shfl(bestBox.x, srcl); wbox.y = __shfl(bestBox.y, srcl);
        wbox.z = __shfl(bestBox.z, srcl); wbox.w = __shfl(bestBox.w, srcl);
        if (lane == 0) {
            warpKey[p][wid]  = wmax;
            warpSlot[p][wid] = wslot;
            warpBox[p][wid]  = wbox;
        }
        __syncthreads();                           // the ONE barrier per iteration

        // every warp redundantly reduces the NW warp-winners (no second barrier)
        unsigned long long ekey = (lane < NW) ? warpKey[p][lane] : 0ull;
        int    eslot = (lane < NW) ? warpSlot[p][lane] : 0;
        float4 ebox  = (lane < NW) ? warpBox[p][lane] : make_float4(0.f,0.f,0.f,0.f);
        unsigned long long fmx = ekey;
        #pragma unroll
        for (int off = 4; off > 0; off >>= 1) {
            unsigned long long o = __shfl_down(fmx, off);
            if (o > fmx) fmx = o;
        }
        fmx = __shfl(fmx, 0);
        if (!(fmx >> 32)) break;                   // no live candidate anywhere (uniform)
        unsigned long long fb = __ballot(lane < NW && ekey == fmx);
        int fl = __ffsll((long long)fb) - 1;
        int fslot = __shfl(eslot, fl);
        float4 fbox;
        fbox.x = __shfl(ebox.x, fl); fbox.y = __shfl(ebox.y, fl);
        fbox.z = __shfl(ebox.z, fl); fbox.w = __shfl(ebox.w, fl);

        if (tid == 0) {
            sS[K]    = __uint_as_float((unsigned)(fmx >> 32));
            sN[K]    = (int)(~(unsigned)fmx);
            sSlot[K] = fslot;
        }
        prev = fbox;
        ++K;
    }

    __syncthreads();
    for (int j = tid; j < K; j += NMS_THREADS) {
        survS[g*NMS_MAX + j] = sS[j];
        survN[g*NMS_MAX + j] = sN[j];
        survB[g*NMS_MAX + j] = rb_ws[g*NCAND + sSlot[j]];
    }
    if (tid == 0) Kout[g] = K;
}

// -------- Phase C: merge per-label survivor lists (640 cap), label-2 first, write out --------
__global__ __launch_bounds__(256) void write_out(
    const int* __restrict__ Kout, const float* __restrict__ survS,
    const int* __restrict__ survN, const float4* __restrict__ survB,
    float* __restrict__ out)
{
    int b = blockIdx.x, tid = threadIdx.x;
    __shared__ int t1s, t2s;
    int g1 = b*2 + 0, g2 = b*2 + 1;
    if (tid == 0) {
        int K1 = Kout[g1], K2 = Kout[g2];
        int take1 = K1, take2 = K2;
        if (K1 + K2 > NMS_MAX) {
            // global selection order = score-desc merge; tie by flat idx (n1 <= n2 => label-1 first)
            const float* s1 = survS + g1*NMS_MAX;
            const float* s2 = survS + g2*NMS_MAX;
            const int*   n1 = survN + g1*NMS_MAX;
            const int*   n2 = survN + g2*NMS_MAX;
            int i1 = 0, i2 = 0;
            for (int k = 0; k < NMS_MAX; ++k) {
                bool p1;
                if (i1 >= K1)      p1 = false;
                else if (i2 >= K2) p1 = true;
                else {
                    float a = s1[i1], c = s2[i2];
                    p1 = (a > c) || (a == c && n1[i1] <= n2[i2]);
                }
                if (p1) ++i1; else ++i2;
            }
            take1 = i1; take2 = i2;
        }
        t1s = take1; t2s = take2;
    }
    __syncthreads();
    int take1 = t1s, take2 = t2s;

    float* ob = out + b*DETS*4;
    float* os = out + B_IMG*DETS*4 + b*DETS;
    float* ol = out + B_IMG*DETS*5 + b*DETS;
    for (int p = tid; p < DETS; p += 256) {
        float4 bx = make_float4(0.f, 0.f, 0.f, 0.f);
        float sv = 0.f, lv = 0.f;
        if (p < take2) {
            int idx = g2*NMS_MAX + p;
            bx = survB[idx]; sv = survS[idx]; lv = 2.f;
        } else if (p - take2 < take1) {
            int idx = g1*NMS_MAX + (p - take2);
            bx = survB[idx]; sv = survS[idx]; lv = 1.f;
        }
        reinterpret_cast<float4*>(ob)[p] = bx;
        os[p] = sv;
        ol[p] = lv;
    }
}

extern "C" void kernel_launch(void* const* d_in, const int* in_sizes, int n_in,
                              void* d_out, int out_size, void* d_ws, size_t ws_size,
                              hipStream_t stream)
{
    const float* logits = (const float*)d_in[0];
    const float* rel    = (const float*)d_in[1];
    const float* props  = (const float*)d_in[2];
    const int*   imgsz  = (const int*)d_in[3];
    float* out = (float*)d_out;
    char*  ws  = (char*)d_ws;

    // workspace layout (~10.75 MB total)
    int*    cnt   = (int*)ws;                                   // 16 ints
    int*    Kout  = (int*)(ws + 64);                            // 16 ints
    float*  survS = (float*)(ws + 4096);                        // 16*640 f32
    int*    survN = (int*)(ws + 4096 + 40960);                  // 16*640 i32
    float4* survB = (float4*)(ws + 4096 + 81920);               // 16*640 f32x4
    float*  sc_ws = (float*)(ws + 262144);                      // 16*16384 f32 (1 MB)
    int*    n_ws  = (int*)(ws + 262144 + 1048576);              // 1 MB
    float4* ob_ws = (float4*)(ws + 262144 + 2097152);           // 4 MB (offset boxes)
    float4* rb_ws = (float4*)(ws + 262144 + 2097152 + 4194304); // 4 MB (raw boxes)

    hipMemsetAsync(cnt, 0, 64, stream);
    decode_compact<<<dim3(512), dim3(256), 0, stream>>>(logits, rel, props, imgsz,
                                                        cnt, sc_ws, n_ws, ob_ws, rb_ws);
    nms_greedy<<<dim3(16), dim3(NMS_THREADS), 0, stream>>>(sc_ws, n_ws, ob_ws, rb_ws,
                                                           cnt, Kout, survS, survN, survB);
    write_out<<<dim3(8), dim3(256), 0, stream>>>(Kout, survS, survN, survB, out);
}

// Round 5
// 1971.453 us; speedup vs baseline: 1.1050x; 1.1050x over previous
//
#include <hip/hip_runtime.h>
#include <cstdint>
#include <math.h>

// Problem constants (fixed by reference setup_inputs)
#define B_IMG   8
#define N_PROP  16384
#define NCAND   16384        // per-(image,label) candidate array stride
#define NMS_MAX 640
#define DETS    320
#define SCORE_TH 0.3f
#define MIN_SZ   0.01f
#define BBOX_CLIP_F 4.135166556742356f   // log(1000/16), same f32 as reference

// Exact threshold for "RN_f32(inter/denom) > 0.3f" without dividing:
// 0.3f = 0x3E99999A (even mantissa), succ = 0x3E99999B.
// q > 0.3f  <=>  inter/denom (real) > midpoint(0.3f, succ)  (tie->even rounds DOWN to 0.3f)
// midpoint exact in f64; (25-bit) x (24-bit) product exact in f64 -> comparison exact.
#define M_TH 0.30000002682209014892578125

#define NMS_THREADS 512
#define NW          (NMS_THREADS/64)     // 8 waves
#define RSLOTS      18                   // named scalar slots/thread -> 9216 capacity
#define REGCAP      (NMS_THREADS*RSLOTS)

// ---- macro-expanded slot state: NO arrays -> no alloca -> guaranteed registers ----
#define FOR18(M) M(0) M(1) M(2) M(3) M(4) M(5) M(6) M(7) M(8) M(9) \
                 M(10) M(11) M(12) M(13) M(14) M(15) M(16) M(17)

#define DECL_SLOT(k) \
    unsigned long long key##k; float bxx##k, bxy##k, bxz##k, bxw##k, aa##k;

#define LOAD_SLOT(k) { \
    int i = (k)*NMS_THREADS + tid; \
    if (i < V) { \
        float s = gsc[i]; \
        key##k = ((unsigned long long)__float_as_uint(s) << 32) | (unsigned)(~nn[i]); \
        float4 bx = obox[i]; \
        bxx##k = bx.x; bxy##k = bx.y; bxz##k = bx.z; bxw##k = bx.w; \
        aa##k = (bx.z - bx.x) * (bx.w - bx.y); \
    } else { \
        key##k = 0ull; bxx##k = 0.f; bxy##k = 0.f; bxz##k = 0.f; bxw##k = 0.f; aa##k = 0.f; \
    } }

#define SWEEP_SLOT(k) \
    if ((k)*NMS_THREADS < V) {                       /* wave-uniform: skip empty tail */ \
        if (key##k) { \
            float ltx = fmaxf(prevx, bxx##k), lty = fmaxf(prevy, bxy##k); \
            float rbx = fminf(prevz, bxz##k), rby = fminf(prevw, bxw##k); \
            float ww = fmaxf(rbx - ltx, 0.f), hh = fmaxf(rby - lty, 0.f); \
            float inter = ww * hh; \
            float denom = (a1 + aa##k) - inter; \
            if ((double)inter > M_TH * (double)denom) {       /* exact: iou > 0.3f */ \
                key##k = 0ull;                                /* suppressed (incl. self) */ \
            } else if (key##k > best) { \
                best = key##k; bslot = (k)*NMS_THREADS + tid; \
                bbx = bxx##k; bby = bxy##k; bbz = bxz##k; bbw = bxw##k; \
            } \
        } \
    }

// -------- Phase A: decode + softmax + validity -> compacted per-(b,label) lists --------
__global__ __launch_bounds__(256) void decode_compact(
    const float* __restrict__ logits, const float* __restrict__ rel,
    const float* __restrict__ props, const int* __restrict__ img_size,
    int* __restrict__ cnt, float* __restrict__ sc_ws, int* __restrict__ n_ws,
    float4* __restrict__ ob_ws, float4* __restrict__ rb_ws)
{
    int t = blockIdx.x * 256 + threadIdx.x;     // t in [0, B*N)
    int b = t >> 14;
    int n = t & (N_PROP - 1);
    float fs = (float)img_size[0];

    float l0 = logits[3*t+0], l1 = logits[3*t+1], l2 = logits[3*t+2];
    float m  = fmaxf(l0, fmaxf(l1, l2));
    float e0 = expf(l0 - m), e1 = expf(l1 - m), e2 = expf(l2 - m);
    float sum = e0 + e1 + e2;
    float p[2] = { e1 / sum, e2 / sum };

    float4 pr = reinterpret_cast<const float4*>(props)[t];
    float w  = pr.z - pr.x, h  = pr.w - pr.y;
    float cx = pr.x + 0.5f*w, cy = pr.y + 0.5f*h;

    const float4* relv = reinterpret_cast<const float4*>(rel) + 3*t;
    int lane = threadIdx.x & 63;
    unsigned long long lanemask = (1ull << lane) - 1ull;

    #pragma unroll
    for (int c = 1; c <= 2; ++c) {
        float4 r = relv[c];
        float dx = r.x / 10.0f, dy = r.y / 10.0f;
        float dw = fminf(r.z / 5.0f, BBOX_CLIP_F);
        float dh = fminf(r.w / 5.0f, BBOX_CLIP_F);
        float pcx = dx * w + cx, pcy = dy * h + cy;
        float pw  = expf(dw) * w, ph  = expf(dh) * h;
        float x1 = pcx - 0.5f*pw, y1 = pcy - 0.5f*ph;
        float x2 = pcx + 0.5f*pw, y2 = pcy + 0.5f*ph;
        x1 = fminf(fmaxf(x1, 0.f), fs); y1 = fminf(fmaxf(y1, 0.f), fs);
        x2 = fminf(fmaxf(x2, 0.f), fs); y2 = fminf(fmaxf(y2, 0.f), fs);
        float sc = p[c-1];
        bool valid = (sc > SCORE_TH) && (x2 - x1 >= MIN_SZ) && (y2 - y1 >= MIN_SZ);

        unsigned long long mball = __ballot(valid);
        int g   = b*2 + (c-1);
        int tot = __popcll(mball);
        int base = 0;
        if (lane == 0 && tot > 0) base = atomicAdd(&cnt[g], tot);
        base = __shfl(base, 0);
        if (valid) {
            int slot = g*NCAND + base + __popcll(mball & lanemask);
            sc_ws[slot] = sc;
            n_ws[slot]  = n;                     // original proposal index (flat idx j = 2n+c-1)
            float off = (float)c * (fs + 1.0f);  // matches reference nboxes bit-for-bit
            ob_ws[slot] = make_float4(x1+off, y1+off, x2+off, y2+off);
            rb_ws[slot] = make_float4(x1, y1, x2, y2);
        }
    }
}

// -------- Phase B: per-(image,label) greedy NMS, named-scalar register residency --------
__global__ __launch_bounds__(NMS_THREADS, 1) void nms_greedy(
    float* __restrict__ sc_ws, const int* __restrict__ n_ws,
    const float4* __restrict__ ob_ws, const float4* __restrict__ rb_ws,
    const int* __restrict__ cnt, int* __restrict__ Kout,
    float* __restrict__ survS, int* __restrict__ survN, float4* __restrict__ survB)
{
    __shared__ unsigned long long warpKey[2][NW];   // parity double-buffer: 1 barrier/iter
    __shared__ int                warpSlot[2][NW];
    __shared__ float4             warpBox[2][NW];
    __shared__ float sS[NMS_MAX];                   // survivors staged in LDS, flushed after loop
    __shared__ int   sN[NMS_MAX];
    __shared__ int   sSlot[NMS_MAX];

    int g   = blockIdx.x;            // g = b*2 + (label-1)
    int tid = threadIdx.x;
    int V   = cnt[g];
    float*        gsc  = sc_ws + g*NCAND;
    const float4* obox = ob_ws + g*NCAND;
    const int*    nn   = n_ws  + g*NCAND;

    FOR18(DECL_SLOT)
    FOR18(LOAD_SLOT)

    float prevx = -2.f, prevy = -2.f, prevz = -1.f, prevw = -1.f;  // dummy: IoU==0 vs all
    int wid = tid >> 6, lane = tid & 63;
    int K = 0;

    for (int it = 0; it < NMS_MAX; ++it) {
        int p = it & 1;
        float a1 = (prevz - prevx) * (prevw - prevy);
        unsigned long long best = 0ull;
        int bslot = 0;
        float bbx = 0.f, bby = 0.f, bbz = 0.f, bbw = 0.f;

        FOR18(SWEEP_SLOT)

        // global tail for V > REGCAP (normally never taken)
        for (int i = REGCAP + tid; i < V; i += NMS_THREADS) {
            float s = gsc[i];
            if (s > 0.f) {
                float4 bx = obox[i];
                float ltx = fmaxf(prevx, bx.x), lty = fmaxf(prevy, bx.y);
                float rbx = fminf(prevz, bx.z), rby = fminf(prevw, bx.w);
                float ww = fmaxf(rbx - ltx, 0.f), hh = fmaxf(rby - lty, 0.f);
                float inter = ww * hh;
                float a2 = (bx.z - bx.x) * (bx.w - bx.y);
                float denom = (a1 + a2) - inter;
                if ((double)inter > M_TH * (double)denom) {
                    gsc[i] = 0.f;
                } else {
                    unsigned long long key =
                        ((unsigned long long)__float_as_uint(s) << 32) | (unsigned)(~nn[i]);
                    if (key > best) { best = key; bslot = i; bbx = bx.x; bby = bx.y; bbz = bx.z; bbw = bx.w; }
                }
            }
        }

        // warp-level max key; winner located by ballot (keys unique: ~n embedded)
        unsigned long long wmax = best;
        #pragma unroll
        for (int off = 32; off > 0; off >>= 1) {
            unsigned long long o = __shfl_down(wmax, off);
            if (o > wmax) wmax = o;
        }
        wmax = __shfl(wmax, 0);
        unsigned long long wb = __ballot(best == wmax && wmax != 0ull);
        int wl = __ffsll((long long)wb) - 1;       // -1 if warp fully dead
        int srcl = (wl < 0) ? 0 : wl;
        int   wslot = __shfl(bslot, srcl);
        float4 wbox;
        wbox.x = __shfl(bbx, srcl); wbox.y = __shfl(bby, srcl);
        wbox.z = __shfl(bbz, srcl); wbox.w = __shfl(bbw, srcl);
        if (lane == 0) {
            warpKey[p][wid]  = wmax;
            warpSlot[p][wid] = wslot;
            warpBox[p][wid]  = wbox;
        }
        __syncthreads();                           // the ONE barrier per iteration

        // every warp redundantly reduces the NW warp-winners (no second barrier)
        unsigned long long ekey = (lane < NW) ? warpKey[p][lane] : 0ull;
        int    eslot = (lane < NW) ? warpSlot[p][lane] : 0;
        float4 ebox  = (lane < NW) ? warpBox[p][lane] : make_float4(0.f,0.f,0.f,0.f);
        unsigned long long fmx = ekey;
        #pragma unroll
        for (int off = 4; off > 0; off >>= 1) {
            unsigned long long o = __shfl_down(fmx, off);
            if (o > fmx) fmx = o;
        }
        fmx = __shfl(fmx, 0);
        if (!(fmx >> 32)) break;                   // no live candidate anywhere (uniform)
        unsigned long long fb = __ballot(lane < NW && ekey == fmx);
        int fl = __ffsll((long long)fb) - 1;
        int fslot = __shfl(eslot, fl);
        prevx = __shfl(ebox.x, fl); prevy = __shfl(ebox.y, fl);
        prevz = __shfl(ebox.z, fl); prevw = __shfl(ebox.w, fl);

        if (tid == 0) {
            sS[K]    = __uint_as_float((unsigned)(fmx >> 32));
            sN[K]    = (int)(~(unsigned)fmx);
            sSlot[K] = fslot;
        }
        ++K;
    }

    __syncthreads();
    for (int j = tid; j < K; j += NMS_THREADS) {
        survS[g*NMS_MAX + j] = sS[j];
        survN[g*NMS_MAX + j] = sN[j];
        survB[g*NMS_MAX + j] = rb_ws[g*NCAND + sSlot[j]];
    }
    if (tid == 0) Kout[g] = K;
}

// -------- Phase C: merge per-label survivor lists (640 cap), label-2 first, write out --------
__global__ __launch_bounds__(256) void write_out(
    const int* __restrict__ Kout, const float* __restrict__ survS,
    const int* __restrict__ survN, const float4* __restrict__ survB,
    float* __restrict__ out)
{
    int b = blockIdx.x, tid = threadIdx.x;
    __shared__ int t1s, t2s;
    int g1 = b*2 + 0, g2 = b*2 + 1;
    if (tid == 0) {
        int K1 = Kout[g1], K2 = Kout[g2];
        int take1 = K1, take2 = K2;
        if (K1 + K2 > NMS_MAX) {
            // global selection order = score-desc merge; tie by flat idx (n1 <= n2 => label-1 first)
            const float* s1 = survS + g1*NMS_MAX;
            const float* s2 = survS + g2*NMS_MAX;
            const int*   n1 = survN + g1*NMS_MAX;
            const int*   n2 = survN + g2*NMS_MAX;
            int i1 = 0, i2 = 0;
            for (int k = 0; k < NMS_MAX; ++k) {
                bool p1;
                if (i1 >= K1)      p1 = false;
                else if (i2 >= K2) p1 = true;
                else {
                    float a = s1[i1], c = s2[i2];
                    p1 = (a > c) || (a == c && n1[i1] <= n2[i2]);
                }
                if (p1) ++i1; else ++i2;
            }
            take1 = i1; take2 = i2;
        }
        t1s = take1; t2s = take2;
    }
    __syncthreads();
    int take1 = t1s, take2 = t2s;

    float* ob = out + b*DETS*4;
    float* os = out + B_IMG*DETS*4 + b*DETS;
    float* ol = out + B_IMG*DETS*5 + b*DETS;
    for (int p = tid; p < DETS; p += 256) {
        float4 bx = make_float4(0.f, 0.f, 0.f, 0.f);
        float sv = 0.f, lv = 0.f;
        if (p < take2) {
            int idx = g2*NMS_MAX + p;
            bx = survB[idx]; sv = survS[idx]; lv = 2.f;
        } else if (p - take2 < take1) {
            int idx = g1*NMS_MAX + (p - take2);
            bx = survB[idx]; sv = survS[idx]; lv = 1.f;
        }
        reinterpret_cast<float4*>(ob)[p] = bx;
        os[p] = sv;
        ol[p] = lv;
    }
}

extern "C" void kernel_launch(void* const* d_in, const int* in_sizes, int n_in,
                              void* d_out, int out_size, void* d_ws, size_t ws_size,
                              hipStream_t stream)
{
    const float* logits = (const float*)d_in[0];
    const float* rel    = (const float*)d_in[1];
    const float* props  = (const float*)d_in[2];
    const int*   imgsz  = (const int*)d_in[3];
    float* out = (float*)d_out;
    char*  ws  = (char*)d_ws;

    // workspace layout (~10.75 MB total)
    int*    cnt   = (int*)ws;                                   // 16 ints
    int*    Kout  = (int*)(ws + 64);                            // 16 ints
    float*  survS = (float*)(ws + 4096);                        // 16*640 f32
    int*    survN = (int*)(ws + 4096 + 40960);                  // 16*640 i32
    float4* survB = (float4*)(ws + 4096 + 81920);               // 16*640 f32x4
    float*  sc_ws = (float*)(ws + 262144);                      // 16*16384 f32 (1 MB)
    int*    n_ws  = (int*)(ws + 262144 + 1048576);              // 1 MB
    float4* ob_ws = (float4*)(ws + 262144 + 2097152);           // 4 MB (offset boxes)
    float4* rb_ws = (float4*)(ws + 262144 + 2097152 + 4194304); // 4 MB (raw boxes)

    hipMemsetAsync(cnt, 0, 64, stream);
    decode_compact<<<dim3(512), dim3(256), 0, stream>>>(logits, rel, props, imgsz,
                                                        cnt, sc_ws, n_ws, ob_ws, rb_ws);
    nms_greedy<<<dim3(16), dim3(NMS_THREADS), 0, stream>>>(sc_ws, n_ws, ob_ws, rb_ws,
                                                           cnt, Kout, survS, survN, survB);
    write_out<<<dim3(8), dim3(256), 0, stream>>>(Kout, survS, survN, survB, out);
}

// Round 6
// 1923.891 us; speedup vs baseline: 1.1324x; 1.0247x over previous
//
#include <hip/hip_runtime.h>
#include <cstdint>
#include <math.h>

// Problem constants (fixed by reference setup_inputs)
#define B_IMG   8
#define N_PROP  16384
#define NCAND   16384        // per-(image,label) candidate array stride
#define NMS_MAX 640
#define DETS    320
#define SCORE_TH 0.3f
#define MIN_SZ   0.01f
#define BBOX_CLIP_F 4.135166556742356f   // log(1000/16), same f32 as reference

// Exact threshold for "RN_f32(inter/denom) > 0.3f" without dividing:
// 0.3f = 0x3E99999A (even mantissa), succ = 0x3E99999B.
// q > 0.3f  <=>  inter/denom (real) > midpoint(0.3f, succ)  (tie->even rounds DOWN to 0.3f)
// midpoint exact in f64; (25-bit) x (24-bit) product exact in f64 -> comparison exact.
#define M_TH 0.30000002682209014892578125

#define NMS_THREADS 1024
#define NW          (NMS_THREADS/64)     // 16 waves
#define RSLOTS      8                    // named scalar slots/thread -> 8192 capacity
#define REGCAP      (NMS_THREADS*RSLOTS)

// ---- macro-expanded slot state: NO arrays -> no alloca; 8x7=56 state VGPRs fits the
// ---- hard 128-VGPR cap of a 16-wave block (4 waves/SIMD) with room for temps ----
#define FOR8(M) M(0) M(1) M(2) M(3) M(4) M(5) M(6) M(7)

#define DECL_SLOT(k) \
    unsigned long long key##k; float bxx##k, bxy##k, bxz##k, bxw##k, aa##k;

#define LOAD_SLOT(k) { \
    int i = (k)*NMS_THREADS + tid; \
    if (i < V) { \
        float s = gsc[i]; \
        key##k = ((unsigned long long)__float_as_uint(s) << 32) | (unsigned)(~nn[i]); \
        float4 bx = obox[i]; \
        bxx##k = bx.x; bxy##k = bx.y; bxz##k = bx.z; bxw##k = bx.w; \
        aa##k = (bx.z - bx.x) * (bx.w - bx.y); \
    } else { \
        key##k = 0ull; bxx##k = 0.f; bxy##k = 0.f; bxz##k = 0.f; bxw##k = 0.f; aa##k = 0.f; \
    } }

#define SWEEP_SLOT(k) \
    if ((k)*NMS_THREADS < V) {                       /* wave-uniform: skip empty tail */ \
        if (key##k) { \
            float ltx = fmaxf(prevx, bxx##k), lty = fmaxf(prevy, bxy##k); \
            float rbx = fminf(prevz, bxz##k), rby = fminf(prevw, bxw##k); \
            float ww = fmaxf(rbx - ltx, 0.f), hh = fmaxf(rby - lty, 0.f); \
            float inter = ww * hh; \
            float denom = (a1 + aa##k) - inter; \
            if ((double)inter > M_TH * (double)denom) {       /* exact: iou > 0.3f */ \
                key##k = 0ull;                                /* suppressed (incl. self) */ \
            } else if (key##k > best) { \
                best = key##k; bslot = (k)*NMS_THREADS + tid; \
                bbx = bxx##k; bby = bxy##k; bbz = bxz##k; bbw = bxw##k; \
            } \
        } \
    }

// -------- Phase A: decode + softmax + validity -> compacted per-(b,label) lists --------
__global__ __launch_bounds__(256) void decode_compact(
    const float* __restrict__ logits, const float* __restrict__ rel,
    const float* __restrict__ props, const int* __restrict__ img_size,
    int* __restrict__ cnt, float* __restrict__ sc_ws, int* __restrict__ n_ws,
    float4* __restrict__ ob_ws, float4* __restrict__ rb_ws)
{
    int t = blockIdx.x * 256 + threadIdx.x;     // t in [0, B*N)
    int b = t >> 14;
    int n = t & (N_PROP - 1);
    float fs = (float)img_size[0];

    float l0 = logits[3*t+0], l1 = logits[3*t+1], l2 = logits[3*t+2];
    float m  = fmaxf(l0, fmaxf(l1, l2));
    float e0 = expf(l0 - m), e1 = expf(l1 - m), e2 = expf(l2 - m);
    float sum = e0 + e1 + e2;
    float p[2] = { e1 / sum, e2 / sum };

    float4 pr = reinterpret_cast<const float4*>(props)[t];
    float w  = pr.z - pr.x, h  = pr.w - pr.y;
    float cx = pr.x + 0.5f*w, cy = pr.y + 0.5f*h;

    const float4* relv = reinterpret_cast<const float4*>(rel) + 3*t;
    int lane = threadIdx.x & 63;
    unsigned long long lanemask = (1ull << lane) - 1ull;

    #pragma unroll
    for (int c = 1; c <= 2; ++c) {
        float4 r = relv[c];
        float dx = r.x / 10.0f, dy = r.y / 10.0f;
        float dw = fminf(r.z / 5.0f, BBOX_CLIP_F);
        float dh = fminf(r.w / 5.0f, BBOX_CLIP_F);
        float pcx = dx * w + cx, pcy = dy * h + cy;
        float pw  = expf(dw) * w, ph  = expf(dh) * h;
        float x1 = pcx - 0.5f*pw, y1 = pcy - 0.5f*ph;
        float x2 = pcx + 0.5f*pw, y2 = pcy + 0.5f*ph;
        x1 = fminf(fmaxf(x1, 0.f), fs); y1 = fminf(fmaxf(y1, 0.f), fs);
        x2 = fminf(fmaxf(x2, 0.f), fs); y2 = fminf(fmaxf(y2, 0.f), fs);
        float sc = p[c-1];
        bool valid = (sc > SCORE_TH) && (x2 - x1 >= MIN_SZ) && (y2 - y1 >= MIN_SZ);

        unsigned long long mball = __ballot(valid);
        int g   = b*2 + (c-1);
        int tot = __popcll(mball);
        int base = 0;
        if (lane == 0 && tot > 0) base = atomicAdd(&cnt[g], tot);
        base = __shfl(base, 0);
        if (valid) {
            int slot = g*NCAND + base + __popcll(mball & lanemask);
            sc_ws[slot] = sc;
            n_ws[slot]  = n;                     // original proposal index (flat idx j = 2n+c-1)
            float off = (float)c * (fs + 1.0f);  // matches reference nboxes bit-for-bit
            ob_ws[slot] = make_float4(x1+off, y1+off, x2+off, y2+off);
            rb_ws[slot] = make_float4(x1, y1, x2, y2);
        }
    }
}

// -------- Phase B: per-(image,label) greedy NMS, named-scalar register residency --------
__global__ __launch_bounds__(NMS_THREADS) void nms_greedy(
    float* __restrict__ sc_ws, const int* __restrict__ n_ws,
    const float4* __restrict__ ob_ws, const float4* __restrict__ rb_ws,
    const int* __restrict__ cnt, int* __restrict__ Kout,
    float* __restrict__ survS, int* __restrict__ survN, float4* __restrict__ survB)
{
    __shared__ unsigned long long warpKey[2][NW];   // parity double-buffer: 1 barrier/iter
    __shared__ int                warpSlot[2][NW];
    __shared__ float4             warpBox[2][NW];
    __shared__ float sS[NMS_MAX];                   // survivors staged in LDS, flushed after loop
    __shared__ int   sN[NMS_MAX];
    __shared__ int   sSlot[NMS_MAX];

    int g   = blockIdx.x;            // g = b*2 + (label-1)
    int tid = threadIdx.x;
    int V   = cnt[g];
    float*        gsc  = sc_ws + g*NCAND;
    const float4* obox = ob_ws + g*NCAND;
    const int*    nn   = n_ws  + g*NCAND;

    FOR8(DECL_SLOT)
    FOR8(LOAD_SLOT)

    float prevx = -2.f, prevy = -2.f, prevz = -1.f, prevw = -1.f;  // dummy: IoU==0 vs all
    int wid = tid >> 6, lane = tid & 63;
    int K = 0;

    for (int it = 0; it < NMS_MAX; ++it) {
        int p = it & 1;
        float a1 = (prevz - prevx) * (prevw - prevy);
        unsigned long long best = 0ull;
        int bslot = 0;
        float bbx = 0.f, bby = 0.f, bbz = 0.f, bbw = 0.f;

        FOR8(SWEEP_SLOT)

        // global tail for V > REGCAP (normally never taken)
        for (int i = REGCAP + tid; i < V; i += NMS_THREADS) {
            float s = gsc[i];
            if (s > 0.f) {
                float4 bx = obox[i];
                float ltx = fmaxf(prevx, bx.x), lty = fmaxf(prevy, bx.y);
                float rbx = fminf(prevz, bx.z), rby = fminf(prevw, bx.w);
                float ww = fmaxf(rbx - ltx, 0.f), hh = fmaxf(rby - lty, 0.f);
                float inter = ww * hh;
                float a2 = (bx.z - bx.x) * (bx.w - bx.y);
                float denom = (a1 + a2) - inter;
                if ((double)inter > M_TH * (double)denom) {
                    gsc[i] = 0.f;
                } else {
                    unsigned long long key =
                        ((unsigned long long)__float_as_uint(s) << 32) | (unsigned)(~nn[i]);
                    if (key > best) { best = key; bslot = i; bbx = bx.x; bby = bx.y; bbz = bx.z; bbw = bx.w; }
                }
            }
        }

        // warp-level max key; winner located by ballot (keys unique: ~n embedded)
        unsigned long long wmax = best;
        #pragma unroll
        for (int off = 32; off > 0; off >>= 1) {
            unsigned long long o = __shfl_down(wmax, off);
            if (o > wmax) wmax = o;
        }
        wmax = __shfl(wmax, 0);
        unsigned long long wb = __ballot(best == wmax && wmax != 0ull);
        int wl = __ffsll((long long)wb) - 1;       // -1 if warp fully dead
        int srcl = (wl < 0) ? 0 : wl;
        int   wslot = __shfl(bslot, srcl);
        float4 wbox;
        wbox.x = __shfl(bbx, srcl); wbox.y = __shfl(bby, srcl);
        wbox.z = __shfl(bbz, srcl); wbox.w = __shfl(bbw, srcl);
        if (lane == 0) {
            warpKey[p][wid]  = wmax;
            warpSlot[p][wid] = wslot;
            warpBox[p][wid]  = wbox;
        }
        __syncthreads();                           // the ONE barrier per iteration

        // every warp redundantly reduces the NW warp-winners (no second barrier)
        unsigned long long ekey = (lane < NW) ? warpKey[p][lane] : 0ull;
        int    eslot = (lane < NW) ? warpSlot[p][lane] : 0;
        float4 ebox  = (lane < NW) ? warpBox[p][lane] : make_float4(0.f,0.f,0.f,0.f);
        unsigned long long fmx = ekey;
        #pragma unroll
        for (int off = NW/2; off > 0; off >>= 1) {
            unsigned long long o = __shfl_down(fmx, off);
            if (o > fmx) fmx = o;
        }
        fmx = __shfl(fmx, 0);
        if (!(fmx >> 32)) break;                   // no live candidate anywhere (uniform)
        unsigned long long fb = __ballot(lane < NW && ekey == fmx);
        int fl = __ffsll((long long)fb) - 1;
        int fslot = __shfl(eslot, fl);
        prevx = __shfl(ebox.x, fl); prevy = __shfl(ebox.y, fl);
        prevz = __shfl(ebox.z, fl); prevw = __shfl(ebox.w, fl);

        if (tid == 0) {
            sS[K]    = __uint_as_float((unsigned)(fmx >> 32));
            sN[K]    = (int)(~(unsigned)fmx);
            sSlot[K] = fslot;
        }
        ++K;
    }

    __syncthreads();
    for (int j = tid; j < K; j += NMS_THREADS) {
        survS[g*NMS_MAX + j] = sS[j];
        survN[g*NMS_MAX + j] = sN[j];
        survB[g*NMS_MAX + j] = rb_ws[g*NCAND + sSlot[j]];
    }
    if (tid == 0) Kout[g] = K;
}

// -------- Phase C: merge per-label survivor lists (640 cap), label-2 first, write out --------
__global__ __launch_bounds__(256) void write_out(
    const int* __restrict__ Kout, const float* __restrict__ survS,
    const int* __restrict__ survN, const float4* __restrict__ survB,
    float* __restrict__ out)
{
    int b = blockIdx.x, tid = threadIdx.x;
    __shared__ int t1s, t2s;
    int g1 = b*2 + 0, g2 = b*2 + 1;
    if (tid == 0) {
        int K1 = Kout[g1], K2 = Kout[g2];
        int take1 = K1, take2 = K2;
        if (K1 + K2 > NMS_MAX) {
            // global selection order = score-desc merge; tie by flat idx (n1 <= n2 => label-1 first)
            const float* s1 = survS + g1*NMS_MAX;
            const float* s2 = survS + g2*NMS_MAX;
            const int*   n1 = survN + g1*NMS_MAX;
            const int*   n2 = survN + g2*NMS_MAX;
            int i1 = 0, i2 = 0;
            for (int k = 0; k < NMS_MAX; ++k) {
                bool p1;
                if (i1 >= K1)      p1 = false;
                else if (i2 >= K2) p1 = true;
                else {
                    float a = s1[i1], c = s2[i2];
                    p1 = (a > c) || (a == c && n1[i1] <= n2[i2]);
                }
                if (p1) ++i1; else ++i2;
            }
            take1 = i1; take2 = i2;
        }
        t1s = take1; t2s = take2;
    }
    __syncthreads();
    int take1 = t1s, take2 = t2s;

    float* ob = out + b*DETS*4;
    float* os = out + B_IMG*DETS*4 + b*DETS;
    float* ol = out + B_IMG*DETS*5 + b*DETS;
    for (int p = tid; p < DETS; p += 256) {
        float4 bx = make_float4(0.f, 0.f, 0.f, 0.f);
        float sv = 0.f, lv = 0.f;
        if (p < take2) {
            int idx = g2*NMS_MAX + p;
            bx = survB[idx]; sv = survS[idx]; lv = 2.f;
        } else if (p - take2 < take1) {
            int idx = g1*NMS_MAX + (p - take2);
            bx = survB[idx]; sv = survS[idx]; lv = 1.f;
        }
        reinterpret_cast<float4*>(ob)[p] = bx;
        os[p] = sv;
        ol[p] = lv;
    }
}

extern "C" void kernel_launch(void* const* d_in, const int* in_sizes, int n_in,
                              void* d_out, int out_size, void* d_ws, size_t ws_size,
                              hipStream_t stream)
{
    const float* logits = (const float*)d_in[0];
    const float* rel    = (const float*)d_in[1];
    const float* props  = (const float*)d_in[2];
    const int*   imgsz  = (const int*)d_in[3];
    float* out = (float*)d_out;
    char*  ws  = (char*)d_ws;

    // workspace layout (~10.75 MB total)
    int*    cnt   = (int*)ws;                                   // 16 ints
    int*    Kout  = (int*)(ws + 64);                            // 16 ints
    float*  survS = (float*)(ws + 4096);                        // 16*640 f32
    int*    survN = (int*)(ws + 4096 + 40960);                  // 16*640 i32
    float4* survB = (float4*)(ws + 4096 + 81920);               // 16*640 f32x4
    float*  sc_ws = (float*)(ws + 262144);                      // 16*16384 f32 (1 MB)
    int*    n_ws  = (int*)(ws + 262144 + 1048576);              // 1 MB
    float4* ob_ws = (float4*)(ws + 262144 + 2097152);           // 4 MB (offset boxes)
    float4* rb_ws = (float4*)(ws + 262144 + 2097152 + 4194304); // 4 MB (raw boxes)

    hipMemsetAsync(cnt, 0, 64, stream);
    decode_compact<<<dim3(512), dim3(256), 0, stream>>>(logits, rel, props, imgsz,
                                                        cnt, sc_ws, n_ws, ob_ws, rb_ws);
    nms_greedy<<<dim3(16), dim3(NMS_THREADS), 0, stream>>>(sc_ws, n_ws, ob_ws, rb_ws,
                                                           cnt, Kout, survS, survN, survB);
    write_out<<<dim3(8), dim3(256), 0, stream>>>(Kout, survS, survN, survB, out);
}

// Round 10
// 599.230 us; speedup vs baseline: 3.6355x; 3.2106x over previous
//
#include <hip/hip_runtime.h>
#include <cstdint>
#include <math.h>

// Problem constants (fixed by reference setup_inputs)
#define B_IMG   8
#define N_PROP  16384
#define NMS_MAX 640
#define DETS    320
#define SCORE_TH 0.3f
#define MIN_SZ   0.01f
#define BBOX_CLIP_F 4.135166556742356f   // log(1000/16), same f32 as reference

// Exact threshold for "RN_f32(inter/denom) > 0.3f" without dividing:
// 0.3f = 0x3E99999A (even mantissa). q > 0.3f <=> real(inter/denom) > midpoint(0.3f, succ)
// (tie->even rounds DOWN). midpoint exact in f64; 25x24-bit product exact in f64.
#define M_TH 0.30000002682209014892578125

#define NMS_THREADS 1024
#define KCAP 8192            // LDS sort capacity; V>KCAP falls back to global 16384 sort

// -------- Phase A: decode + softmax + validity -> packed keys (compacted) + boxes by n --------
__global__ __launch_bounds__(256) void decode_compact(
    const float* __restrict__ logits, const float* __restrict__ rel,
    const float* __restrict__ props, const int* __restrict__ img_size,
    int* __restrict__ cnt, unsigned long long* __restrict__ keys_ws,
    float4* __restrict__ obByN, float4* __restrict__ rbByN)
{
    int t = blockIdx.x * 256 + threadIdx.x;     // t in [0, B*N)
    int b = t >> 14;
    int n = t & (N_PROP - 1);
    float fs = (float)img_size[0];

    float l0 = logits[3*t+0], l1 = logits[3*t+1], l2 = logits[3*t+2];
    float m  = fmaxf(l0, fmaxf(l1, l2));
    float e0 = expf(l0 - m), e1 = expf(l1 - m), e2 = expf(l2 - m);
    float sum = e0 + e1 + e2;
    float p[2] = { e1 / sum, e2 / sum };

    float4 pr = reinterpret_cast<const float4*>(props)[t];
    float w  = pr.z - pr.x, h  = pr.w - pr.y;
    float cx = pr.x + 0.5f*w, cy = pr.y + 0.5f*h;

    const float4* relv = reinterpret_cast<const float4*>(rel) + 3*t;
    int lane = threadIdx.x & 63;
    unsigned long long lanemask = (1ull << lane) - 1ull;

    #pragma unroll
    for (int c = 1; c <= 2; ++c) {
        float4 r = relv[c];
        float dx = r.x / 10.0f, dy = r.y / 10.0f;
        float dw = fminf(r.z / 5.0f, BBOX_CLIP_F);
        float dh = fminf(r.w / 5.0f, BBOX_CLIP_F);
        float pcx = dx * w + cx, pcy = dy * h + cy;
        float pw  = expf(dw) * w, ph  = expf(dh) * h;
        float x1 = pcx - 0.5f*pw, y1 = pcy - 0.5f*ph;
        float x2 = pcx + 0.5f*pw, y2 = pcy + 0.5f*ph;
        x1 = fminf(fmaxf(x1, 0.f), fs); y1 = fminf(fmaxf(y1, 0.f), fs);
        x2 = fminf(fmaxf(x2, 0.f), fs); y2 = fminf(fmaxf(y2, 0.f), fs);
        float sc = p[c-1];
        bool valid = (sc > SCORE_TH) && (x2 - x1 >= MIN_SZ) && (y2 - y1 >= MIN_SZ);

        int g = b*2 + (c-1);
        float off = (float)c * (fs + 1.0f);      // matches reference nboxes bit-for-bit
        obByN[g*N_PROP + n] = make_float4(x1+off, y1+off, x2+off, y2+off);
        rbByN[g*N_PROP + n] = make_float4(x1, y1, x2, y2);

        unsigned long long mball = __ballot(valid);
        int tot = __popcll(mball);
        int base = 0;
        if (lane == 0 && tot > 0) base = atomicAdd(&cnt[g], tot);
        base = __shfl(base, 0);
        if (valid) {
            int slot = base + __popcll(mball & lanemask);
            // key: (score desc, n asc) under u64 desc order; pad keys (0) sort last
            keys_ws[(size_t)g*N_PROP + slot] =
                ((unsigned long long)__float_as_uint(sc) << 14) | (unsigned)(16383 - n);
        }
    }
}

// -------- Phase B: sort (bitonic desc) + chunked greedy scan --------
__global__ __launch_bounds__(NMS_THREADS) void nms_sorted(
    unsigned long long* __restrict__ keys_ws,
    const float4* __restrict__ obByN, const float4* __restrict__ rbByN,
    const int* __restrict__ cnt, int* __restrict__ Kout,
    float* __restrict__ survS, int* __restrict__ survN, float4* __restrict__ survB)
{
    __shared__ unsigned long long Klds[KCAP];          // 64 KB
    __shared__ float4 cbox[64];
    __shared__ float  carea[64];
    __shared__ unsigned long long Wmat[64];            // W[k] bit j: k suppresses j (j>k, in-chunk)
    __shared__ unsigned long long chunkRem;            // rows of chunk removed by kept list
    __shared__ unsigned long long newKeptMask;
    __shared__ float4 keptB[NMS_MAX];                  // offset boxes of kept (for IoU)
    __shared__ float  keptA[NMS_MAX];
    __shared__ unsigned long long keptKey[NMS_MAX];
    __shared__ int keptTotS, keptBaseS;

    int g   = blockIdx.x;                              // g = b*2 + (label-1)
    int tid = threadIdx.x;
    int V   = cnt[g];
    unsigned long long* Kg = keys_ws + (size_t)g*N_PROP;
    const float4* obox = obByN + (size_t)g*N_PROP;
    int lane = tid & 63;

    bool useLds = (V <= KCAP);
    if (useLds) {
        for (int i = tid; i < KCAP; i += NMS_THREADS) Klds[i] = (i < V) ? Kg[i] : 0ull;
    } else {
        for (int i = V + tid; i < N_PROP; i += NMS_THREADS) Kg[i] = 0ull;   // pad
    }
    if (tid == 0) keptTotS = 0;
    __syncthreads();

    // ---- bitonic sort, descending (classic i^j network with flipped comparisons) ----
    if (useLds) {
        for (int k2 = 2; k2 <= KCAP; k2 <<= 1)
            for (int j = k2 >> 1; j > 0; j >>= 1) {
                for (int i = tid; i < KCAP; i += NMS_THREADS) {
                    int ixj = i ^ j;
                    if (ixj > i) {
                        unsigned long long a = Klds[i], b = Klds[ixj];
                        if (((i & k2) == 0) ? (a < b) : (a > b)) { Klds[i] = b; Klds[ixj] = a; }
                    }
                }
                __syncthreads();
            }
    } else {                                           // structural fallback (not expected)
        for (int k2 = 2; k2 <= N_PROP; k2 <<= 1)
            for (int j = k2 >> 1; j > 0; j >>= 1) {
                for (int i = tid; i < N_PROP; i += NMS_THREADS) {
                    int ixj = i ^ j;
                    if (ixj > i) {
                        unsigned long long a = Kg[i], b = Kg[ixj];
                        if (((i & k2) == 0) ? (a < b) : (a > b)) { Kg[i] = b; Kg[ixj] = a; }
                    }
                }
                __syncthreads();
            }
    }

    // ---- chunked greedy scan over sorted order ----
    int keptTot = 0;
    for (int cbase = 0; cbase < V; cbase += 64) {
        int cn = min(64, V - cbase);

        // phase 1: load chunk boxes (gather by n), init masks
        if (tid < 64) {
            Wmat[tid] = 0ull;
            if (tid < cn) {
                unsigned long long key = useLds ? Klds[cbase + tid] : Kg[cbase + tid];
                int n = 16383 - (int)(key & 16383u);
                float4 bx = obox[n];
                cbox[tid]  = bx;
                carea[tid] = (bx.z - bx.x) * (bx.w - bx.y);
            }
        }
        if (tid == 0) chunkRem = 0ull;
        __syncthreads();

        // phase 2a: in-chunk pairwise suppression matrix (k < j < cn)
        for (int p = tid; p < 64*64; p += NMS_THREADS) {
            int j = p >> 6, k = p & 63;
            if (k < j && j < cn) {
                float4 bj = cbox[j], bk = cbox[k];
                float ltx = fmaxf(bk.x, bj.x), lty = fmaxf(bk.y, bj.y);
                float rbx = fminf(bk.z, bj.z), rby = fminf(bk.w, bj.w);
                float ww = fmaxf(rbx - ltx, 0.f), hh = fmaxf(rby - lty, 0.f);
                float inter = ww * hh;
                float denom = (carea[k] + carea[j]) - inter;
                if ((double)inter > M_TH * (double)denom)
                    atomicOr(&Wmat[k], 1ull << j);
            }
        }
        // phase 2b: chunk rows vs kept-so-far boxes
        unsigned long long localRem = 0ull;
        for (int p = tid; p < 64*keptTot; p += NMS_THREADS) {
            int j = p & 63, k = p >> 6;
            if (j < cn) {
                float4 bj = cbox[j], bk = keptB[k];
                float ltx = fmaxf(bk.x, bj.x), lty = fmaxf(bk.y, bj.y);
                float rbx = fminf(bk.z, bj.z), rby = fminf(bk.w, bj.w);
                float ww = fmaxf(rbx - ltx, 0.f), hh = fmaxf(rby - lty, 0.f);
                float inter = ww * hh;
                float denom = (keptA[k] + carea[j]) - inter;
                if ((double)inter > M_TH * (double)denom) localRem |= 1ull << j;
            }
        }
        #pragma unroll
        for (int off = 32; off > 0; off >>= 1) localRem |= __shfl_down(localRem, off);
        if (lane == 0 && localRem) atomicOr(&chunkRem, localRem);
        __syncthreads();

        // phase 3: serial in-chunk resolve (bit ops only)
        if (tid == 0) {
            unsigned long long alive = ~chunkRem;
            if (cn < 64) alive &= ((1ull << cn) - 1ull);
            unsigned long long km = 0ull;
            int kt = keptTot;
            while (alive && kt < NMS_MAX) {
                int k = __ffsll((long long)alive) - 1;
                km |= 1ull << k;
                alive &= ~(1ull << k);
                alive &= ~Wmat[k];
                ++kt;
            }
            newKeptMask = km;
            keptBaseS = keptTot;
            keptTotS = kt;
        }
        __syncthreads();

        // phase 4: append newly-kept
        unsigned long long km = newKeptMask;
        if (tid < 64 && ((km >> tid) & 1ull)) {
            int rank = __popcll(km & ((1ull << tid) - 1ull));
            int idx  = keptBaseS + rank;
            keptB[idx]   = cbox[tid];
            keptA[idx]   = carea[tid];
            keptKey[idx] = useLds ? Klds[cbase + tid] : Kg[cbase + tid];
        }
        __syncthreads();
        keptTot = keptTotS;
        if (keptTot >= NMS_MAX) break;
    }

    // ---- flush survivors (desc score order by construction) ----
    const float4* rbox = rbByN + (size_t)g*N_PROP;
    for (int jj = tid; jj < keptTot; jj += NMS_THREADS) {
        unsigned long long key = keptKey[jj];
        int n = 16383 - (int)(key & 16383u);
        survS[g*NMS_MAX + jj] = __uint_as_float((unsigned)(key >> 14));
        survN[g*NMS_MAX + jj] = n;
        survB[g*NMS_MAX + jj] = rbox[n];
    }
    if (tid == 0) Kout[g] = keptTot;
}

// -------- Phase C: merge per-label survivor lists (640 cap), label-2 first, write out --------
__global__ __launch_bounds__(256) void write_out(
    const int* __restrict__ Kout, const float* __restrict__ survS,
    const int* __restrict__ survN, const float4* __restrict__ survB,
    float* __restrict__ out)
{
    int b = blockIdx.x, tid = threadIdx.x;
    __shared__ int t1s, t2s;
    int g1 = b*2 + 0, g2 = b*2 + 1;
    if (tid == 0) {
        int K1 = Kout[g1], K2 = Kout[g2];
        int take1 = K1, take2 = K2;
        if (K1 + K2 > NMS_MAX) {
            // global selection order = score-desc merge; tie by flat idx (n1 <= n2 => label-1 first)
            const float* s1 = survS + g1*NMS_MAX;
            const float* s2 = survS + g2*NMS_MAX;
            const int*   n1 = survN + g1*NMS_MAX;
            const int*   n2 = survN + g2*NMS_MAX;
            int i1 = 0, i2 = 0;
            for (int k = 0; k < NMS_MAX; ++k) {
                bool p1;
                if (i1 >= K1)      p1 = false;
                else if (i2 >= K2) p1 = true;
                else {
                    float a = s1[i1], c = s2[i2];
                    p1 = (a > c) || (a == c && n1[i1] <= n2[i2]);
                }
                if (p1) ++i1; else ++i2;
            }
            take1 = i1; take2 = i2;
        }
        t1s = take1; t2s = take2;
    }
    __syncthreads();
    int take1 = t1s, take2 = t2s;

    float* ob = out + b*DETS*4;
    float* os = out + B_IMG*DETS*4 + b*DETS;
    float* ol = out + B_IMG*DETS*5 + b*DETS;
    for (int p = tid; p < DETS; p += 256) {
        float4 bx = make_float4(0.f, 0.f, 0.f, 0.f);
        float sv = 0.f, lv = 0.f;
        if (p < take2) {
            int idx = g2*NMS_MAX + p;
            bx = survB[idx]; sv = survS[idx]; lv = 2.f;
        } else if (p - take2 < take1) {
            int idx = g1*NMS_MAX + (p - take2);
            bx = survB[idx]; sv = survS[idx]; lv = 1.f;
        }
        reinterpret_cast<float4*>(ob)[p] = bx;
        os[p] = sv;
        ol[p] = lv;
    }
}

extern "C" void kernel_launch(void* const* d_in, const int* in_sizes, int n_in,
                              void* d_out, int out_size, void* d_ws, size_t ws_size,
                              hipStream_t stream)
{
    const float* logits = (const float*)d_in[0];
    const float* rel    = (const float*)d_in[1];
    const float* props  = (const float*)d_in[2];
    const int*   imgsz  = (const int*)d_in[3];
    float* out = (float*)d_out;
    char*  ws  = (char*)d_ws;

    // workspace layout (~10.3 MB total)
    int*    cnt   = (int*)ws;                                   // 16 ints
    int*    Kout  = (int*)(ws + 64);                            // 16 ints
    float*  survS = (float*)(ws + 4096);                        // 16*640 f32
    int*    survN = (int*)(ws + 4096 + 40960);                  // 16*640 i32
    float4* survB = (float4*)(ws + 4096 + 81920);               // 16*640 f32x4
    unsigned long long* keys_ws = (unsigned long long*)(ws + 262144);   // 16*16384 u64 (2 MB)
    float4* obByN = (float4*)(ws + 262144 + 2097152);           // 4 MB (offset boxes by n)
    float4* rbByN = (float4*)(ws + 262144 + 2097152 + 4194304); // 4 MB (raw boxes by n)

    hipMemsetAsync(cnt, 0, 64, stream);
    decode_compact<<<dim3(512), dim3(256), 0, stream>>>(logits, rel, props, imgsz,
                                                        cnt, keys_ws, obByN, rbByN);
    nms_sorted<<<dim3(16), dim3(NMS_THREADS), 0, stream>>>(keys_ws, obByN, rbByN,
                                                           cnt, Kout, survS, survN, survB);
    write_out<<<dim3(8), dim3(256), 0, stream>>>(Kout, survS, survN, survB, out);
}